// Round 3
// baseline (500.867 us; speedup 1.0000x reference)
//
#include <hip/hip_runtime.h>
#include <cstdint>
#include <cstddef>

// ---------------------------------------------------------------------------
// DeepIM: VAE (matvec chain) + 2-layer GAT on 1%-dense adjacency.
//  - GAT heads are rank-1 => logits e[i,j]=leaky(c1*xh[i]+c2*xh[j]); head
//    outputs collapse to scalars. No NxN / Nx64 intermediates.
//  - adjacency -> 2MB bitmap (permuted bit mapping from uint4 ballots).
//  - Round 3: ONE persistent cooperative kernel (512 blocks x 256 thr,
//    __launch_bounds__(256,2) -> 2 blocks/CU guaranteed co-resident) with 7
//    hand-rolled grid barriers. Weights for stage k+1 are prefetched into
//    registers BEFORE barrier k (BW hides under barrier wait); conv is spread
//    across stages S1-S5 as background BW work; bitmap rows live in registers
//    between gat_heads and gat_out. Fallback: round-2 multi-kernel pipeline.
// ---------------------------------------------------------------------------

typedef unsigned long long u64;

#define ACT_NONE 0
#define ACT_RELU 1
#define ACT_SIG  2

__device__ __forceinline__ float d4(float4 a, float4 b) {
  return a.x * b.x + a.y * b.y + a.z * b.z + a.w * b.w;
}
__device__ __forceinline__ float waveRed(float v) {
  for (int o = 32; o; o >>= 1) v += __shfl_down(v, o);
  return v;  // lane 0 holds sum
}

// Hand-rolled single-use grid barrier (counter pre-zeroed by prep kernel).
__device__ __forceinline__ void gridbar(unsigned* cnt, unsigned nblk) {
  __syncthreads();
  if (threadIdx.x == 0) {
    __threadfence();                 // release: block's writes visible device-wide
    atomicAdd(cnt, 1u);              // device-scope
    while (__hip_atomic_load(cnt, __ATOMIC_ACQUIRE, __HIP_MEMORY_SCOPE_AGENT) < nblk)
      __builtin_amdgcn_s_sleep(2);
    __threadfence();                 // acquire
  }
  __syncthreads();
}

// conv: one adjacency row -> 64 bitmap words, permuted mapping:
//   bm word q (=it*4+c), bit b  <->  column (q>>2)*256 + 4*b + (q&3)
__device__ __forceinline__ void convRowInt(const uint4* aw, u64* bm, int r, int lane) {
  const uint4* rp = aw + (size_t)r * 1024u;
#pragma unroll
  for (int it = 0; it < 16; ++it) {
    const uint4 v = rp[it * 64 + lane];
    const u64 m0 = __ballot(v.x != 0u);
    const u64 m1 = __ballot(v.y != 0u);
    const u64 m2 = __ballot(v.z != 0u);
    const u64 m3 = __ballot(v.w != 0u);
    if (lane < 4) {
      const u64 mv = lane == 0 ? m0 : lane == 1 ? m1 : lane == 2 ? m2 : m3;
      bm[(size_t)r * 64 + it * 4 + lane] = mv;
    }
  }
}
__device__ __forceinline__ void convRowByte(const uint32_t* ab, u64* bm, int r, int lane) {
  const uint32_t* rp = ab + (size_t)r * 1024u;  // 4096 bytes
#pragma unroll
  for (int it = 0; it < 16; ++it) {
    const uint32_t v = rp[it * 64 + lane];
    const u64 m0 = __ballot((v & 0x000000ffu) != 0u);
    const u64 m1 = __ballot((v & 0x0000ff00u) != 0u);
    const u64 m2 = __ballot((v & 0x00ff0000u) != 0u);
    const u64 m3 = __ballot((v & 0xff000000u) != 0u);
    if (lane < 4) {
      const u64 mv = lane == 0 ? m0 : lane == 1 ? m1 : lane == 2 ? m2 : m3;
      bm[(size_t)r * 64 + it * 4 + lane] = mv;
    }
  }
}
__device__ __forceinline__ void convRow(const void* adj, int fl, u64* bm, int r, int lane) {
  if (fl) convRowByte((const uint32_t*)adj, bm, r, lane);
  else    convRowInt((const uint4*)adj, bm, r, lane);
}

struct P {
  const float *x, *eps;
  const void* adj;
  const float *w1, *b1, *w2, *b2, *w3, *b3, *w4, *b4;
  const float *dw1, *db1, *dw2, *db2, *dw3, *db3;
  float *xhat, *yhat, *mu, *logvar;
  u64* bm;
  float *h1, *h2, *h3, *h4, *wh2, *consts;
  const int* flag;
  unsigned* bars;
};

__global__ __launch_bounds__(256, 2) void fused_kernel(P p) {
  const int b = blockIdx.x, tid = threadIdx.x;
  const int w = tid >> 6, lane = tid & 63;
  const unsigned nblk = gridDim.x;
  const int fl = *p.flag;
  __shared__ float red[4][8];
  __shared__ float zs[512];
  const int cA = b * 8 + w * 2, cB = cA + 1;  // this wave's conv/gat rows

  // ---- S1: enc1 rows {b,b+512}; conv wave0:rowA; prefetch w2
  {
    float a0 = 0.f, a1 = 0.f;
    const float4* x4 = (const float4*)p.x;
    const float4* r0 = (const float4*)(p.w1 + (size_t)b * 4096u);
    const float4* r1 = (const float4*)(p.w1 + (size_t)(b + 512) * 4096u);
#pragma unroll
    for (int k = 0; k < 4; ++k) {
      const int idx = tid + 256 * k;
      const float4 xv = x4[idx];
      a0 += d4(r0[idx], xv);
      a1 += d4(r1[idx], xv);
    }
    a0 = waveRed(a0); a1 = waveRed(a1);
    if (lane == 0) { red[w][0] = a0; red[w][1] = a1; }
    __syncthreads();
    if (tid < 2) {
      const int r = b + 512 * tid;
      const float v = red[0][tid] + red[1][tid] + red[2][tid] + red[3][tid] + p.b1[r];
      p.h1[r] = v > 0.f ? v : 0.f;
    }
  }
  if (w == 0) convRow(p.adj, fl, p.bm, cA, lane);
  float4 pA = ((const float4*)(p.w2 + (size_t)b * 1024u))[tid];
  float4 pB = ((const float4*)(p.w2 + (size_t)(b + 512) * 1024u))[tid];
  gridbar(&p.bars[0], nblk);

  // ---- S2: enc2 rows {b,b+512}; conv wave1; prefetch w3/w4 row b
  {
    const float4 hv = ((const float4*)p.h1)[tid];
    float a0 = waveRed(d4(pA, hv)), a1 = waveRed(d4(pB, hv));
    if (lane == 0) { red[w][0] = a0; red[w][1] = a1; }
    __syncthreads();
    if (tid < 2) {
      const int r = b + 512 * tid;
      const float v = red[0][tid] + red[1][tid] + red[2][tid] + red[3][tid] + p.b2[r];
      p.h2[r] = v > 0.f ? v : 0.f;
    }
  }
  if (w == 1) { convRow(p.adj, fl, p.bm, cA, lane); convRow(p.adj, fl, p.bm, cB, lane); }
  pA = ((const float4*)(p.w3 + (size_t)b * 1024u))[tid];
  pB = ((const float4*)(p.w4 + (size_t)b * 1024u))[tid];
  gridbar(&p.bars[1], nblk);

  // ---- S3: mu[b], logvar[b]; conv wave2; prefetch dw1 rows {b,b+512}
  {
    const float4 hv = ((const float4*)p.h2)[tid];
    float a0 = waveRed(d4(pA, hv)), a1 = waveRed(d4(pB, hv));
    if (lane == 0) { red[w][0] = a0; red[w][1] = a1; }
    __syncthreads();
    if (tid == 0) p.mu[b]     = red[0][0] + red[1][0] + red[2][0] + red[3][0] + p.b3[b];
    if (tid == 1) p.logvar[b] = red[0][1] + red[1][1] + red[2][1] + red[3][1] + p.b4[b];
  }
  if (w == 2) { convRow(p.adj, fl, p.bm, cA, lane); convRow(p.adj, fl, p.bm, cB, lane); }
  float2 qA = ((const float2*)(p.dw1 + (size_t)b * 512u))[tid];
  float2 qB = ((const float2*)(p.dw1 + (size_t)(b + 512) * 512u))[tid];
  gridbar(&p.bars[2], nblk);

  // ---- S4: z in LDS; dec1 rows {b,b+512}; conv wave3; prefetch dw2
  {
    zs[tid]       = p.mu[tid]       + p.eps[tid]       * expf(0.5f * p.logvar[tid]);
    zs[tid + 256] = p.mu[tid + 256] + p.eps[tid + 256] * expf(0.5f * p.logvar[tid + 256]);
    __syncthreads();
    float a0 = qA.x * zs[2 * tid] + qA.y * zs[2 * tid + 1];
    float a1 = qB.x * zs[2 * tid] + qB.y * zs[2 * tid + 1];
    a0 = waveRed(a0); a1 = waveRed(a1);
    if (lane == 0) { red[w][0] = a0; red[w][1] = a1; }
    __syncthreads();
    if (tid < 2) {
      const int r = b + 512 * tid;
      const float v = red[0][tid] + red[1][tid] + red[2][tid] + red[3][tid] + p.db1[r];
      p.h3[r] = v > 0.f ? v : 0.f;
    }
  }
  if (w == 3) { convRow(p.adj, fl, p.bm, cA, lane); convRow(p.adj, fl, p.bm, cB, lane); }
  pA = ((const float4*)(p.dw2 + (size_t)b * 1024u))[tid];
  pB = ((const float4*)(p.dw2 + (size_t)(b + 512) * 1024u))[tid];
  gridbar(&p.bars[3], nblk);

  // ---- S5: dec2 rows {b,b+512}; conv wave0:rowB; prefetch dw3 (8 rows)
  {
    const float4 hv = ((const float4*)p.h3)[tid];
    float a0 = waveRed(d4(pA, hv)), a1 = waveRed(d4(pB, hv));
    if (lane == 0) { red[w][0] = a0; red[w][1] = a1; }
    __syncthreads();
    if (tid < 2) {
      const int r = b + 512 * tid;
      const float v = red[0][tid] + red[1][tid] + red[2][tid] + red[3][tid] + p.db2[r];
      p.h4[r] = v > 0.f ? v : 0.f;
    }
  }
  if (w == 0) convRow(p.adj, fl, p.bm, cB, lane);
  float4 pw[8];
#pragma unroll
  for (int k = 0; k < 8; ++k)
    pw[k] = ((const float4*)(p.dw3 + (size_t)(b + 512 * k) * 1024u))[tid];
  gridbar(&p.bars[4], nblk);

  // ---- S6: dec3+sigmoid rows b+512k; prefetch bitmap rows for GAT
  {
    const float4 hv = ((const float4*)p.h4)[tid];
    float acc[8];
#pragma unroll
    for (int k = 0; k < 8; ++k) acc[k] = waveRed(d4(pw[k], hv));
    if (lane == 0) {
#pragma unroll
      for (int k = 0; k < 8; ++k) red[w][k] = acc[k];
    }
    __syncthreads();
    if (tid < 8) {
      const int r = b + 512 * tid;
      const float v = red[0][tid] + red[1][tid] + red[2][tid] + red[3][tid] + p.db3[r];
      p.xhat[r] = 1.f / (1.f + expf(-v));
    }
  }
  const u64 mA = p.bm[(size_t)cA * 64 + lane];
  const u64 mB = p.bm[(size_t)cB * 64 + lane];
  gridbar(&p.bars[5], nblk);

  // ---- S7: gat heads (4 fused) rows cA,cB -> wh2
  {
    const float c10 = p.consts[0], c11 = p.consts[1], c12 = p.consts[2], c13 = p.consts[3];
    const float c20 = p.consts[4], c21 = p.consts[5], c22 = p.consts[6], c23 = p.consts[7];
    const float d0 = p.consts[8], d1 = p.consts[9], d2 = p.consts[10], d3 = p.consts[11];
    const int qbase = ((lane >> 2) << 8) | (lane & 3);
#pragma unroll
    for (int rr = 0; rr < 2; ++rr) {
      const int i = rr ? cB : cA;
      u64 m = rr ? mB : mA;
      const float xi = p.xhat[i];
      const float A0 = c10 * xi, A1 = c11 * xi, A2 = c12 * xi, A3 = c13 * xi;
      float s0 = 0, s1 = 0, s2 = 0, s3 = 0, t0 = 0, t1 = 0, t2 = 0, t3 = 0;
      while (m) {
        const int bp = __builtin_ctzll(m);
        m &= m - 1;
        const float xj = p.xhat[qbase + (bp << 2)];
        float e0 = A0 + c20 * xj, e1 = A1 + c21 * xj, e2 = A2 + c22 * xj, e3 = A3 + c23 * xj;
        e0 = fmaxf(e0, 0.2f * e0); e1 = fmaxf(e1, 0.2f * e1);
        e2 = fmaxf(e2, 0.2f * e2); e3 = fmaxf(e3, 0.2f * e3);
        const float w0 = expf(e0), w1 = expf(e1), w2 = expf(e2), w3 = expf(e3);
        s0 += w0; s1 += w1; s2 += w2; s3 += w3;
        t0 += w0 * xj; t1 += w1 * xj; t2 += w2 * xj; t3 += w3 * xj;
      }
      for (int o = 1; o < 64; o <<= 1) {
        s0 += __shfl_xor(s0, o); s1 += __shfl_xor(s1, o);
        s2 += __shfl_xor(s2, o); s3 += __shfl_xor(s3, o);
        t0 += __shfl_xor(t0, o); t1 += __shfl_xor(t1, o);
        t2 += __shfl_xor(t2, o); t3 += __shfl_xor(t3, o);
      }
      float r0, r1, r2, r3;
      if (s0 != 0.f) { r0 = t0 / s0; r1 = t1 / s1; r2 = t2 / s2; r3 = t3 / s3; }
      else {  // empty row -> uniform attention (mean of xhat); P ~ 0, kept for exactness
        float a = 0.f;
        for (int k = lane; k < 4096; k += 64) a += p.xhat[k];
        for (int o = 1; o < 64; o <<= 1) a += __shfl_xor(a, o);
        r0 = r1 = r2 = r3 = a * (1.f / 4096.f);
      }
      if (lane == 0) p.wh2[i] = d0 * r0 + d1 * r1 + d2 * r2 + d3 * r3;
    }
  }
  gridbar(&p.bars[6], nblk);

  // ---- S8: gat out rows cA,cB -> yhat (elu)
  {
    const float oa0 = p.consts[12], oa1 = p.consts[13];
    const int qbase = ((lane >> 2) << 8) | (lane & 3);
#pragma unroll
    for (int rr = 0; rr < 2; ++rr) {
      const int i = rr ? cB : cA;
      u64 m = rr ? mB : mA;
      const float Ai = oa0 * p.wh2[i];
      float s = 0.f, t = 0.f;
      while (m) {
        const int bp = __builtin_ctzll(m);
        m &= m - 1;
        const float wj = p.wh2[qbase + (bp << 2)];
        float e = Ai + oa1 * wj;
        e = fmaxf(e, 0.2f * e);
        const float ww = expf(e);
        s += ww; t += ww * wj;
      }
      for (int o = 1; o < 64; o <<= 1) {
        s += __shfl_xor(s, o);
        t += __shfl_xor(t, o);
      }
      float v;
      if (s != 0.f) v = t / s;
      else {
        float a = 0.f;
        for (int k = lane; k < 4096; k += 64) a += p.wh2[k];
        for (int o = 1; o < 64; o <<= 1) a += __shfl_xor(a, o);
        v = a * (1.f / 4096.f);
      }
      if (lane == 0) p.yhat[i] = v > 0.f ? v : expm1f(v);
    }
  }
}

// Per-head scalars + adjacency format sniff + barrier-counter zeroing.
__global__ __launch_bounds__(256) void prep_sniff_kernel(const float* __restrict__ gw,
    const float* __restrict__ ga, const float* __restrict__ ow,
    const float* __restrict__ oa, const uint32_t* __restrict__ aw,
    float* __restrict__ consts, int* __restrict__ flag, unsigned* __restrict__ bars) {
  const int t = threadIdx.x, h = t >> 6, k = t & 63;
  if (t < 8 * 16) bars[t] = 0u;  // zero all barrier slots (stride-16 uints)
  const float w = gw[h * 64 + k];
  float p1 = w * ga[h * 128 + k];
  float p2 = w * ga[h * 128 + 64 + k];
  float p3 = w * ow[h * 64 + k];
  for (int off = 32; off; off >>= 1) {
    p1 += __shfl_down(p1, off);
    p2 += __shfl_down(p2, off);
    p3 += __shfl_down(p3, off);
  }
  if (k == 0) { consts[h] = p1; consts[4 + h] = p2; consts[8 + h] = p3; }
  if (t == 0) { consts[12] = oa[0]; consts[13] = oa[1]; }
  // sniff first 64KB (in-bounds under either layout):
  // any word not in {0,1,1.0f} proves packed-byte layout.
  int bad = 0;
  for (int i = t; i < 16384; i += 256) {
    const uint32_t v = aw[i];
    bad |= (v > 1u) && (v != 0x3F800000u);
  }
  __shared__ int lds[4];
  const unsigned long long mm = __ballot(bad);
  if ((t & 63) == 0) lds[t >> 6] = (mm != 0ull) ? 1 : 0;
  __syncthreads();
  if (t == 0) flag[0] = lds[0] | lds[1] | lds[2] | lds[3];
}

// ===================== round-2 fallback pipeline (proven 59 µs) =============
template<int ACT>
__global__ __launch_bounds__(256) void mv_kernel(const float* __restrict__ W,
    const float* __restrict__ x, const float* __restrict__ b,
    float* __restrict__ y, int C) {
  const int r = blockIdx.x;
  const float* row = W + (size_t)r * (size_t)C;
  float acc = 0.f;
  for (int c = threadIdx.x * 4; c < C; c += 256 * 4) {
    const float4 w4 = *reinterpret_cast<const float4*>(row + c);
    const float4 x4 = *reinterpret_cast<const float4*>(x + c);
    acc += d4(w4, x4);
  }
  acc = waveRed(acc);
  __shared__ float lds[4];
  if ((threadIdx.x & 63) == 0) lds[threadIdx.x >> 6] = acc;
  __syncthreads();
  if (threadIdx.x == 0) {
    float v = lds[0] + lds[1] + lds[2] + lds[3] + b[r];
    if (ACT == ACT_RELU) v = v > 0.f ? v : 0.f;
    if (ACT == ACT_SIG)  v = 1.f / (1.f + expf(-v));
    y[r] = v;
  }
}

__global__ __launch_bounds__(256) void mulv_kernel(const float* __restrict__ w3,
    const float* __restrict__ b3, const float* __restrict__ w4,
    const float* __restrict__ b4, const float* __restrict__ h2,
    float* __restrict__ mu, float* __restrict__ logvar) {
  const int r = blockIdx.x;
  const bool is_mu = r < 512;
  const int rr = is_mu ? r : r - 512;
  const float* row = (is_mu ? w3 : w4) + (size_t)rr * 1024u;
  const int c = threadIdx.x * 4;
  float acc = d4(*reinterpret_cast<const float4*>(row + c),
                 *reinterpret_cast<const float4*>(h2 + c));
  acc = waveRed(acc);
  __shared__ float lds[4];
  if ((threadIdx.x & 63) == 0) lds[threadIdx.x >> 6] = acc;
  __syncthreads();
  if (threadIdx.x == 0) {
    const float v = lds[0] + lds[1] + lds[2] + lds[3] + (is_mu ? b3[rr] : b4[rr]);
    (is_mu ? mu : logvar)[rr] = v;
  }
}

__global__ __launch_bounds__(256) void dec1_kernel(const float* __restrict__ W,
    const float* __restrict__ mu, const float* __restrict__ logvar,
    const float* __restrict__ eps, const float* __restrict__ b,
    float* __restrict__ y) {
  __shared__ float zsh[512];
  for (int k = threadIdx.x; k < 512; k += 256)
    zsh[k] = mu[k] + eps[k] * expf(0.5f * logvar[k]);
  __syncthreads();
  const int r = blockIdx.x;
  const float* row = W + (size_t)r * 512u;
  const int c = threadIdx.x * 2;
  const float2 w2 = *reinterpret_cast<const float2*>(row + c);
  float acc = w2.x * zsh[c] + w2.y * zsh[c + 1];
  acc = waveRed(acc);
  __shared__ float lds[4];
  if ((threadIdx.x & 63) == 0) lds[threadIdx.x >> 6] = acc;
  __syncthreads();
  if (threadIdx.x == 0) {
    float v = lds[0] + lds[1] + lds[2] + lds[3] + b[r];
    y[r] = v > 0.f ? v : 0.f;
  }
}

__global__ __launch_bounds__(256) void conv_kernel(const void* __restrict__ adj,
    const int* __restrict__ flag, u64* __restrict__ bm) {
  const int i = blockIdx.x * 4 + (threadIdx.x >> 6);
  convRow(adj, *flag, bm, i, threadIdx.x & 63);
}

__global__ __launch_bounds__(256) void gat_heads_bm(const u64* __restrict__ bm,
    const float* __restrict__ xh, const float* __restrict__ consts,
    float* __restrict__ wh2) {
  const int lane = threadIdx.x & 63;
  const int i = blockIdx.x * 4 + (threadIdx.x >> 6);
  const float xi = xh[i];
  const float A0 = consts[0] * xi, A1 = consts[1] * xi,
              A2 = consts[2] * xi, A3 = consts[3] * xi;
  const float c20 = consts[4], c21 = consts[5], c22 = consts[6], c23 = consts[7];
  float s0 = 0, s1 = 0, s2 = 0, s3 = 0, t0 = 0, t1 = 0, t2 = 0, t3 = 0;
  u64 m = bm[(size_t)i * 64 + lane];
  const int qbase = ((lane >> 2) << 8) | (lane & 3);
  while (m) {
    const int bp = __builtin_ctzll(m);
    m &= m - 1;
    const float xj = xh[qbase + (bp << 2)];
    float e0 = A0 + c20 * xj, e1 = A1 + c21 * xj, e2 = A2 + c22 * xj, e3 = A3 + c23 * xj;
    e0 = fmaxf(e0, 0.2f * e0); e1 = fmaxf(e1, 0.2f * e1);
    e2 = fmaxf(e2, 0.2f * e2); e3 = fmaxf(e3, 0.2f * e3);
    const float w0 = expf(e0), w1 = expf(e1), w2 = expf(e2), w3 = expf(e3);
    s0 += w0; s1 += w1; s2 += w2; s3 += w3;
    t0 += w0 * xj; t1 += w1 * xj; t2 += w2 * xj; t3 += w3 * xj;
  }
  for (int o = 1; o < 64; o <<= 1) {
    s0 += __shfl_xor(s0, o); s1 += __shfl_xor(s1, o);
    s2 += __shfl_xor(s2, o); s3 += __shfl_xor(s3, o);
    t0 += __shfl_xor(t0, o); t1 += __shfl_xor(t1, o);
    t2 += __shfl_xor(t2, o); t3 += __shfl_xor(t3, o);
  }
  float r0, r1, r2, r3;
  if (s0 != 0.f) { r0 = t0 / s0; r1 = t1 / s1; r2 = t2 / s2; r3 = t3 / s3; }
  else {
    float a = 0.f;
    for (int k = lane; k < 4096; k += 64) a += xh[k];
    for (int o = 1; o < 64; o <<= 1) a += __shfl_xor(a, o);
    r0 = r1 = r2 = r3 = a * (1.f / 4096.f);
  }
  if (lane == 0)
    wh2[i] = consts[8] * r0 + consts[9] * r1 + consts[10] * r2 + consts[11] * r3;
}

__global__ __launch_bounds__(256) void gat_out_bm(const u64* __restrict__ bm,
    const float* __restrict__ wh2, const float* __restrict__ consts,
    float* __restrict__ yhat) {
  const int lane = threadIdx.x & 63;
  const int i = blockIdx.x * 4 + (threadIdx.x >> 6);
  const float Ai = consts[12] * wh2[i];
  const float oa1 = consts[13];
  float s = 0.f, t = 0.f;
  u64 m = bm[(size_t)i * 64 + lane];
  const int qbase = ((lane >> 2) << 8) | (lane & 3);
  while (m) {
    const int bp = __builtin_ctzll(m);
    m &= m - 1;
    const float wj = wh2[qbase + (bp << 2)];
    float e = Ai + oa1 * wj;
    e = fmaxf(e, 0.2f * e);
    const float ww = expf(e);
    s += ww; t += ww * wj;
  }
  for (int o = 1; o < 64; o <<= 1) {
    s += __shfl_xor(s, o);
    t += __shfl_xor(t, o);
  }
  float v;
  if (s != 0.f) v = t / s;
  else {
    float a = 0.f;
    for (int k = lane; k < 4096; k += 64) a += wh2[k];
    for (int o = 1; o < 64; o <<= 1) a += __shfl_xor(a, o);
    v = a * (1.f / 4096.f);
  }
  if (lane == 0) yhat[i] = v > 0.f ? v : expm1f(v);
}
// =============================================================================

extern "C" void kernel_launch(void* const* d_in, const int* in_sizes, int n_in,
                              void* d_out, int out_size, void* d_ws, size_t ws_size,
                              hipStream_t stream) {
  const float* x      = (const float*)d_in[0];
  const float* eps    = (const float*)d_in[1];
  const void*  adj    = d_in[2];
  const float* enc_w1 = (const float*)d_in[3];
  const float* enc_b1 = (const float*)d_in[4];
  const float* enc_w2 = (const float*)d_in[5];
  const float* enc_b2 = (const float*)d_in[6];
  const float* enc_w3 = (const float*)d_in[7];
  const float* enc_b3 = (const float*)d_in[8];
  const float* enc_w4 = (const float*)d_in[9];
  const float* enc_b4 = (const float*)d_in[10];
  const float* dec_w1 = (const float*)d_in[11];
  const float* dec_b1 = (const float*)d_in[12];
  const float* dec_w2 = (const float*)d_in[13];
  const float* dec_b2 = (const float*)d_in[14];
  const float* dec_w3 = (const float*)d_in[15];
  const float* dec_b3 = (const float*)d_in[16];
  const float* gat_W  = (const float*)d_in[17];
  const float* gat_a  = (const float*)d_in[18];
  const float* out_W  = (const float*)d_in[19];
  const float* out_a  = (const float*)d_in[20];

  float* out    = (float*)d_out;
  float* xhat   = out;          // [0,4096)
  float* yhat   = out + 4096;   // [4096,8192)
  float* mu     = out + 8192;   // [8192,8704)
  float* logvar = out + 8704;   // [8704,9216)

  const size_t BM_BYTES = (size_t)4096 * 64 * sizeof(u64);  // 2 MiB
  u64*      bm     = (u64*)d_ws;
  float*    F      = (float*)((char*)d_ws + BM_BYTES);
  float*    h1     = F;            // 1024
  float*    h2     = F + 1024;     // 1024
  float*    h3     = F + 2048;     // 1024
  float*    h4     = F + 3072;     // 1024
  float*    wh2    = F + 4096;     // 4096
  float*    consts = F + 8208;     // 14
  int*      flag   = (int*)(F + 8224);
  unsigned* bars   = (unsigned*)(F + 8240);  // 8 slots x 16 uints

  prep_sniff_kernel<<<1, 256, 0, stream>>>(gat_W, gat_a, out_W, out_a,
                                           (const uint32_t*)adj, consts, flag, bars);

  P prm;
  prm.x = x; prm.eps = eps; prm.adj = adj;
  prm.w1 = enc_w1; prm.b1 = enc_b1; prm.w2 = enc_w2; prm.b2 = enc_b2;
  prm.w3 = enc_w3; prm.b3 = enc_b3; prm.w4 = enc_w4; prm.b4 = enc_b4;
  prm.dw1 = dec_w1; prm.db1 = dec_b1; prm.dw2 = dec_w2; prm.db2 = dec_b2;
  prm.dw3 = dec_w3; prm.db3 = dec_b3;
  prm.xhat = xhat; prm.yhat = yhat; prm.mu = mu; prm.logvar = logvar;
  prm.bm = bm; prm.h1 = h1; prm.h2 = h2; prm.h3 = h3; prm.h4 = h4;
  prm.wh2 = wh2; prm.consts = consts; prm.flag = flag; prm.bars = bars;
  void* kargs[] = { (void*)&prm };

  const hipError_t ce = hipLaunchCooperativeKernel(
      (const void*)fused_kernel, dim3(512), dim3(256), kargs, 0, stream);

  if (ce != hipSuccess) {
    // -------- fallback: proven round-2 multi-kernel pipeline --------
    conv_kernel<<<1024, 256, 0, stream>>>(adj, flag, bm);
    mv_kernel<ACT_RELU><<<1024, 256, 0, stream>>>(enc_w1, x,  enc_b1, h1, 4096);
    mv_kernel<ACT_RELU><<<1024, 256, 0, stream>>>(enc_w2, h1, enc_b2, h2, 1024);
    mulv_kernel<<<1024, 256, 0, stream>>>(enc_w3, enc_b3, enc_w4, enc_b4, h2, mu, logvar);
    dec1_kernel<<<1024, 256, 0, stream>>>(dec_w1, mu, logvar, eps, dec_b1, h3);
    mv_kernel<ACT_RELU><<<1024, 256, 0, stream>>>(dec_w2, h3, dec_b2, h4, 1024);
    mv_kernel<ACT_SIG ><<<4096, 256, 0, stream>>>(dec_w3, h4, dec_b3, xhat, 1024);
    gat_heads_bm<<<1024, 256, 0, stream>>>(bm, xhat, consts, wh2);
    gat_out_bm<<<1024, 256, 0, stream>>>(bm, wh2, consts, yhat);
  }
}

// Round 4
// 483.926 us; speedup vs baseline: 1.0350x; 1.0350x over previous
//
#include <hip/hip_runtime.h>
#include <cstdint>
#include <cstddef>

// ---------------------------------------------------------------------------
// DeepIM: VAE (matvec chain) + 2-layer GAT on 1%-dense adjacency.
//  - GAT heads are rank-1 => logits e[i,j]=leaky(c1*xh[i]+c2*xh[j]); head
//    outputs collapse to scalars. No NxN / Nx64 intermediates.
//  - adjacency -> 2MB bitmap (permuted bit mapping from uint4 ballots).
//  - Round 3: ONE persistent cooperative kernel (512 blocks x 256 thr,
//    __launch_bounds__(256,2) -> 2 blocks/CU guaranteed co-resident) with 7
//    hand-rolled grid barriers. Weights for stage k+1 are prefetched into
//    registers BEFORE barrier k (BW hides under barrier wait); conv is spread
//    across stages S1-S5 as background BW work; bitmap rows live in registers
//    between gat_heads and gat_out. Fallback: round-2 multi-kernel pipeline.
// ---------------------------------------------------------------------------

typedef unsigned long long u64;

#define ACT_NONE 0
#define ACT_RELU 1
#define ACT_SIG  2

__device__ __forceinline__ float d4(float4 a, float4 b) {
  return a.x * b.x + a.y * b.y + a.z * b.z + a.w * b.w;
}
__device__ __forceinline__ float waveRed(float v) {
  for (int o = 32; o; o >>= 1) v += __shfl_down(v, o);
  return v;  // lane 0 holds sum
}

// Hand-rolled single-use grid barrier (counter pre-zeroed by prep kernel).
__device__ __forceinline__ void gridbar(unsigned* cnt, unsigned nblk) {
  __syncthreads();
  if (threadIdx.x == 0) {
    __threadfence();                 // release: block's writes visible device-wide
    atomicAdd(cnt, 1u);              // device-scope
    while (__hip_atomic_load(cnt, __ATOMIC_ACQUIRE, __HIP_MEMORY_SCOPE_AGENT) < nblk)
      __builtin_amdgcn_s_sleep(2);
    __threadfence();                 // acquire
  }
  __syncthreads();
}

// conv: one adjacency row -> 64 bitmap words, permuted mapping:
//   bm word q (=it*4+c), bit b  <->  column (q>>2)*256 + 4*b + (q&3)
__device__ __forceinline__ void convRowInt(const uint4* aw, u64* bm, int r, int lane) {
  const uint4* rp = aw + (size_t)r * 1024u;
#pragma unroll
  for (int it = 0; it < 16; ++it) {
    const uint4 v = rp[it * 64 + lane];
    const u64 m0 = __ballot(v.x != 0u);
    const u64 m1 = __ballot(v.y != 0u);
    const u64 m2 = __ballot(v.z != 0u);
    const u64 m3 = __ballot(v.w != 0u);
    if (lane < 4) {
      const u64 mv = lane == 0 ? m0 : lane == 1 ? m1 : lane == 2 ? m2 : m3;
      bm[(size_t)r * 64 + it * 4 + lane] = mv;
    }
  }
}
__device__ __forceinline__ void convRowByte(const uint32_t* ab, u64* bm, int r, int lane) {
  const uint32_t* rp = ab + (size_t)r * 1024u;  // 4096 bytes
#pragma unroll
  for (int it = 0; it < 16; ++it) {
    const uint32_t v = rp[it * 64 + lane];
    const u64 m0 = __ballot((v & 0x000000ffu) != 0u);
    const u64 m1 = __ballot((v & 0x0000ff00u) != 0u);
    const u64 m2 = __ballot((v & 0x00ff0000u) != 0u);
    const u64 m3 = __ballot((v & 0xff000000u) != 0u);
    if (lane < 4) {
      const u64 mv = lane == 0 ? m0 : lane == 1 ? m1 : lane == 2 ? m2 : m3;
      bm[(size_t)r * 64 + it * 4 + lane] = mv;
    }
  }
}
__device__ __forceinline__ void convRow(const void* adj, int fl, u64* bm, int r, int lane) {
  if (fl) convRowByte((const uint32_t*)adj, bm, r, lane);
  else    convRowInt((const uint4*)adj, bm, r, lane);
}

struct P {
  const float *x, *eps;
  const void* adj;
  const float *w1, *b1, *w2, *b2, *w3, *b3, *w4, *b4;
  const float *dw1, *db1, *dw2, *db2, *dw3, *db3;
  float *xhat, *yhat, *mu, *logvar;
  u64* bm;
  float *h1, *h2, *h3, *h4, *wh2, *consts;
  const int* flag;
  unsigned* bars;
};

__global__ __launch_bounds__(256, 2) void fused_kernel(P p) {
  const int b = blockIdx.x, tid = threadIdx.x;
  const int w = tid >> 6, lane = tid & 63;
  const unsigned nblk = gridDim.x;
  const int fl = *p.flag;
  __shared__ float red[4][8];
  __shared__ float zs[512];
  const int cA = b * 8 + w * 2, cB = cA + 1;  // this wave's conv/gat rows

  // ---- S1: enc1 rows {b,b+512}; conv wave0:rowA; prefetch w2
  {
    float a0 = 0.f, a1 = 0.f;
    const float4* x4 = (const float4*)p.x;
    const float4* r0 = (const float4*)(p.w1 + (size_t)b * 4096u);
    const float4* r1 = (const float4*)(p.w1 + (size_t)(b + 512) * 4096u);
#pragma unroll
    for (int k = 0; k < 4; ++k) {
      const int idx = tid + 256 * k;
      const float4 xv = x4[idx];
      a0 += d4(r0[idx], xv);
      a1 += d4(r1[idx], xv);
    }
    a0 = waveRed(a0); a1 = waveRed(a1);
    if (lane == 0) { red[w][0] = a0; red[w][1] = a1; }
    __syncthreads();
    if (tid < 2) {
      const int r = b + 512 * tid;
      const float v = red[0][tid] + red[1][tid] + red[2][tid] + red[3][tid] + p.b1[r];
      p.h1[r] = v > 0.f ? v : 0.f;
    }
  }
  if (w == 0) convRow(p.adj, fl, p.bm, cA, lane);
  float4 pA = ((const float4*)(p.w2 + (size_t)b * 1024u))[tid];
  float4 pB = ((const float4*)(p.w2 + (size_t)(b + 512) * 1024u))[tid];
  gridbar(&p.bars[0], nblk);

  // ---- S2: enc2 rows {b,b+512}; conv wave1; prefetch w3/w4 row b
  {
    const float4 hv = ((const float4*)p.h1)[tid];
    float a0 = waveRed(d4(pA, hv)), a1 = waveRed(d4(pB, hv));
    if (lane == 0) { red[w][0] = a0; red[w][1] = a1; }
    __syncthreads();
    if (tid < 2) {
      const int r = b + 512 * tid;
      const float v = red[0][tid] + red[1][tid] + red[2][tid] + red[3][tid] + p.b2[r];
      p.h2[r] = v > 0.f ? v : 0.f;
    }
  }
  if (w == 1) { convRow(p.adj, fl, p.bm, cA, lane); convRow(p.adj, fl, p.bm, cB, lane); }
  pA = ((const float4*)(p.w3 + (size_t)b * 1024u))[tid];
  pB = ((const float4*)(p.w4 + (size_t)b * 1024u))[tid];
  gridbar(&p.bars[1], nblk);

  // ---- S3: mu[b], logvar[b]; conv wave2; prefetch dw1 rows {b,b+512}
  {
    const float4 hv = ((const float4*)p.h2)[tid];
    float a0 = waveRed(d4(pA, hv)), a1 = waveRed(d4(pB, hv));
    if (lane == 0) { red[w][0] = a0; red[w][1] = a1; }
    __syncthreads();
    if (tid == 0) p.mu[b]     = red[0][0] + red[1][0] + red[2][0] + red[3][0] + p.b3[b];
    if (tid == 1) p.logvar[b] = red[0][1] + red[1][1] + red[2][1] + red[3][1] + p.b4[b];
  }
  if (w == 2) { convRow(p.adj, fl, p.bm, cA, lane); convRow(p.adj, fl, p.bm, cB, lane); }
  float2 qA = ((const float2*)(p.dw1 + (size_t)b * 512u))[tid];
  float2 qB = ((const float2*)(p.dw1 + (size_t)(b + 512) * 512u))[tid];
  gridbar(&p.bars[2], nblk);

  // ---- S4: z in LDS; dec1 rows {b,b+512}; conv wave3; prefetch dw2
  {
    zs[tid]       = p.mu[tid]       + p.eps[tid]       * expf(0.5f * p.logvar[tid]);
    zs[tid + 256] = p.mu[tid + 256] + p.eps[tid + 256] * expf(0.5f * p.logvar[tid + 256]);
    __syncthreads();
    float a0 = qA.x * zs[2 * tid] + qA.y * zs[2 * tid + 1];
    float a1 = qB.x * zs[2 * tid] + qB.y * zs[2 * tid + 1];
    a0 = waveRed(a0); a1 = waveRed(a1);
    if (lane == 0) { red[w][0] = a0; red[w][1] = a1; }
    __syncthreads();
    if (tid < 2) {
      const int r = b + 512 * tid;
      const float v = red[0][tid] + red[1][tid] + red[2][tid] + red[3][tid] + p.db1[r];
      p.h3[r] = v > 0.f ? v : 0.f;
    }
  }
  if (w == 3) { convRow(p.adj, fl, p.bm, cA, lane); convRow(p.adj, fl, p.bm, cB, lane); }
  pA = ((const float4*)(p.dw2 + (size_t)b * 1024u))[tid];
  pB = ((const float4*)(p.dw2 + (size_t)(b + 512) * 1024u))[tid];
  gridbar(&p.bars[3], nblk);

  // ---- S5: dec2 rows {b,b+512}; conv wave0:rowB; prefetch dw3 (8 rows)
  {
    const float4 hv = ((const float4*)p.h3)[tid];
    float a0 = waveRed(d4(pA, hv)), a1 = waveRed(d4(pB, hv));
    if (lane == 0) { red[w][0] = a0; red[w][1] = a1; }
    __syncthreads();
    if (tid < 2) {
      const int r = b + 512 * tid;
      const float v = red[0][tid] + red[1][tid] + red[2][tid] + red[3][tid] + p.db2[r];
      p.h4[r] = v > 0.f ? v : 0.f;
    }
  }
  if (w == 0) convRow(p.adj, fl, p.bm, cB, lane);
  float4 pw[8];
#pragma unroll
  for (int k = 0; k < 8; ++k)
    pw[k] = ((const float4*)(p.dw3 + (size_t)(b + 512 * k) * 1024u))[tid];
  gridbar(&p.bars[4], nblk);

  // ---- S6: dec3+sigmoid rows b+512k; prefetch bitmap rows for GAT
  {
    const float4 hv = ((const float4*)p.h4)[tid];
    float acc[8];
#pragma unroll
    for (int k = 0; k < 8; ++k) acc[k] = waveRed(d4(pw[k], hv));
    if (lane == 0) {
#pragma unroll
      for (int k = 0; k < 8; ++k) red[w][k] = acc[k];
    }
    __syncthreads();
    if (tid < 8) {
      const int r = b + 512 * tid;
      const float v = red[0][tid] + red[1][tid] + red[2][tid] + red[3][tid] + p.db3[r];
      p.xhat[r] = 1.f / (1.f + expf(-v));
    }
  }
  const u64 mA = p.bm[(size_t)cA * 64 + lane];
  const u64 mB = p.bm[(size_t)cB * 64 + lane];
  gridbar(&p.bars[5], nblk);

  // ---- S7: gat heads (4 fused) rows cA,cB -> wh2
  {
    const float c10 = p.consts[0], c11 = p.consts[1], c12 = p.consts[2], c13 = p.consts[3];
    const float c20 = p.consts[4], c21 = p.consts[5], c22 = p.consts[6], c23 = p.consts[7];
    const float d0 = p.consts[8], d1 = p.consts[9], d2 = p.consts[10], d3 = p.consts[11];
    const int qbase = ((lane >> 2) << 8) | (lane & 3);
#pragma unroll
    for (int rr = 0; rr < 2; ++rr) {
      const int i = rr ? cB : cA;
      u64 m = rr ? mB : mA;
      const float xi = p.xhat[i];
      const float A0 = c10 * xi, A1 = c11 * xi, A2 = c12 * xi, A3 = c13 * xi;
      float s0 = 0, s1 = 0, s2 = 0, s3 = 0, t0 = 0, t1 = 0, t2 = 0, t3 = 0;
      while (m) {
        const int bp = __builtin_ctzll(m);
        m &= m - 1;
        const float xj = p.xhat[qbase + (bp << 2)];
        float e0 = A0 + c20 * xj, e1 = A1 + c21 * xj, e2 = A2 + c22 * xj, e3 = A3 + c23 * xj;
        e0 = fmaxf(e0, 0.2f * e0); e1 = fmaxf(e1, 0.2f * e1);
        e2 = fmaxf(e2, 0.2f * e2); e3 = fmaxf(e3, 0.2f * e3);
        const float w0 = expf(e0), w1 = expf(e1), w2 = expf(e2), w3 = expf(e3);
        s0 += w0; s1 += w1; s2 += w2; s3 += w3;
        t0 += w0 * xj; t1 += w1 * xj; t2 += w2 * xj; t3 += w3 * xj;
      }
      for (int o = 1; o < 64; o <<= 1) {
        s0 += __shfl_xor(s0, o); s1 += __shfl_xor(s1, o);
        s2 += __shfl_xor(s2, o); s3 += __shfl_xor(s3, o);
        t0 += __shfl_xor(t0, o); t1 += __shfl_xor(t1, o);
        t2 += __shfl_xor(t2, o); t3 += __shfl_xor(t3, o);
      }
      float r0, r1, r2, r3;
      if (s0 != 0.f) { r0 = t0 / s0; r1 = t1 / s1; r2 = t2 / s2; r3 = t3 / s3; }
      else {  // empty row -> uniform attention (mean of xhat); P ~ 0, kept for exactness
        float a = 0.f;
        for (int k = lane; k < 4096; k += 64) a += p.xhat[k];
        for (int o = 1; o < 64; o <<= 1) a += __shfl_xor(a, o);
        r0 = r1 = r2 = r3 = a * (1.f / 4096.f);
      }
      if (lane == 0) p.wh2[i] = d0 * r0 + d1 * r1 + d2 * r2 + d3 * r3;
    }
  }
  gridbar(&p.bars[6], nblk);

  // ---- S8: gat out rows cA,cB -> yhat (elu)
  {
    const float oa0 = p.consts[12], oa1 = p.consts[13];
    const int qbase = ((lane >> 2) << 8) | (lane & 3);
#pragma unroll
    for (int rr = 0; rr < 2; ++rr) {
      const int i = rr ? cB : cA;
      u64 m = rr ? mB : mA;
      const float Ai = oa0 * p.wh2[i];
      float s = 0.f, t = 0.f;
      while (m) {
        const int bp = __builtin_ctzll(m);
        m &= m - 1;
        const float wj = p.wh2[qbase + (bp << 2)];
        float e = Ai + oa1 * wj;
        e = fmaxf(e, 0.2f * e);
        const float ww = expf(e);
        s += ww; t += ww * wj;
      }
      for (int o = 1; o < 64; o <<= 1) {
        s += __shfl_xor(s, o);
        t += __shfl_xor(t, o);
      }
      float v;
      if (s != 0.f) v = t / s;
      else {
        float a = 0.f;
        for (int k = lane; k < 4096; k += 64) a += p.wh2[k];
        for (int o = 1; o < 64; o <<= 1) a += __shfl_xor(a, o);
        v = a * (1.f / 4096.f);
      }
      if (lane == 0) p.yhat[i] = v > 0.f ? v : expm1f(v);
    }
  }
}

// Per-head scalars + adjacency format sniff + barrier-counter zeroing.
__global__ __launch_bounds__(256) void prep_sniff_kernel(const float* __restrict__ gw,
    const float* __restrict__ ga, const float* __restrict__ ow,
    const float* __restrict__ oa, const uint32_t* __restrict__ aw,
    float* __restrict__ consts, int* __restrict__ flag, unsigned* __restrict__ bars) {
  const int t = threadIdx.x, h = t >> 6, k = t & 63;
  if (t < 8 * 16) bars[t] = 0u;  // zero all barrier slots (stride-16 uints)
  const float w = gw[h * 64 + k];
  float p1 = w * ga[h * 128 + k];
  float p2 = w * ga[h * 128 + 64 + k];
  float p3 = w * ow[h * 64 + k];
  for (int off = 32; off; off >>= 1) {
    p1 += __shfl_down(p1, off);
    p2 += __shfl_down(p2, off);
    p3 += __shfl_down(p3, off);
  }
  if (k == 0) { consts[h] = p1; consts[4 + h] = p2; consts[8 + h] = p3; }
  if (t == 0) { consts[12] = oa[0]; consts[13] = oa[1]; }
  // sniff first 64KB (in-bounds under either layout):
  // any word not in {0,1,1.0f} proves packed-byte layout.
  int bad = 0;
  for (int i = t; i < 16384; i += 256) {
    const uint32_t v = aw[i];
    bad |= (v > 1u) && (v != 0x3F800000u);
  }
  __shared__ int lds[4];
  const unsigned long long mm = __ballot(bad);
  if ((t & 63) == 0) lds[t >> 6] = (mm != 0ull) ? 1 : 0;
  __syncthreads();
  if (t == 0) flag[0] = lds[0] | lds[1] | lds[2] | lds[3];
}

// ===================== round-2 fallback pipeline (proven 59 µs) =============
template<int ACT>
__global__ __launch_bounds__(256) void mv_kernel(const float* __restrict__ W,
    const float* __restrict__ x, const float* __restrict__ b,
    float* __restrict__ y, int C) {
  const int r = blockIdx.x;
  const float* row = W + (size_t)r * (size_t)C;
  float acc = 0.f;
  for (int c = threadIdx.x * 4; c < C; c += 256 * 4) {
    const float4 w4 = *reinterpret_cast<const float4*>(row + c);
    const float4 x4 = *reinterpret_cast<const float4*>(x + c);
    acc += d4(w4, x4);
  }
  acc = waveRed(acc);
  __shared__ float lds[4];
  if ((threadIdx.x & 63) == 0) lds[threadIdx.x >> 6] = acc;
  __syncthreads();
  if (threadIdx.x == 0) {
    float v = lds[0] + lds[1] + lds[2] + lds[3] + b[r];
    if (ACT == ACT_RELU) v = v > 0.f ? v : 0.f;
    if (ACT == ACT_SIG)  v = 1.f / (1.f + expf(-v));
    y[r] = v;
  }
}

__global__ __launch_bounds__(256) void mulv_kernel(const float* __restrict__ w3,
    const float* __restrict__ b3, const float* __restrict__ w4,
    const float* __restrict__ b4, const float* __restrict__ h2,
    float* __restrict__ mu, float* __restrict__ logvar) {
  const int r = blockIdx.x;
  const bool is_mu = r < 512;
  const int rr = is_mu ? r : r - 512;
  const float* row = (is_mu ? w3 : w4) + (size_t)rr * 1024u;
  const int c = threadIdx.x * 4;
  float acc = d4(*reinterpret_cast<const float4*>(row + c),
                 *reinterpret_cast<const float4*>(h2 + c));
  acc = waveRed(acc);
  __shared__ float lds[4];
  if ((threadIdx.x & 63) == 0) lds[threadIdx.x >> 6] = acc;
  __syncthreads();
  if (threadIdx.x == 0) {
    const float v = lds[0] + lds[1] + lds[2] + lds[3] + (is_mu ? b3[rr] : b4[rr]);
    (is_mu ? mu : logvar)[rr] = v;
  }
}

__global__ __launch_bounds__(256) void dec1_kernel(const float* __restrict__ W,
    const float* __restrict__ mu, const float* __restrict__ logvar,
    const float* __restrict__ eps, const float* __restrict__ b,
    float* __restrict__ y) {
  __shared__ float zsh[512];
  for (int k = threadIdx.x; k < 512; k += 256)
    zsh[k] = mu[k] + eps[k] * expf(0.5f * logvar[k]);
  __syncthreads();
  const int r = blockIdx.x;
  const float* row = W + (size_t)r * 512u;
  const int c = threadIdx.x * 2;
  const float2 w2 = *reinterpret_cast<const float2*>(row + c);
  float acc = w2.x * zsh[c] + w2.y * zsh[c + 1];
  acc = waveRed(acc);
  __shared__ float lds[4];
  if ((threadIdx.x & 63) == 0) lds[threadIdx.x >> 6] = acc;
  __syncthreads();
  if (threadIdx.x == 0) {
    float v = lds[0] + lds[1] + lds[2] + lds[3] + b[r];
    y[r] = v > 0.f ? v : 0.f;
  }
}

__global__ __launch_bounds__(256) void conv_kernel(const void* __restrict__ adj,
    const int* __restrict__ flag, u64* __restrict__ bm) {
  const int i = blockIdx.x * 4 + (threadIdx.x >> 6);
  convRow(adj, *flag, bm, i, threadIdx.x & 63);
}

__global__ __launch_bounds__(256) void gat_heads_bm(const u64* __restrict__ bm,
    const float* __restrict__ xh, const float* __restrict__ consts,
    float* __restrict__ wh2) {
  const int lane = threadIdx.x & 63;
  const int i = blockIdx.x * 4 + (threadIdx.x >> 6);
  const float xi = xh[i];
  const float A0 = consts[0] * xi, A1 = consts[1] * xi,
              A2 = consts[2] * xi, A3 = consts[3] * xi;
  const float c20 = consts[4], c21 = consts[5], c22 = consts[6], c23 = consts[7];
  float s0 = 0, s1 = 0, s2 = 0, s3 = 0, t0 = 0, t1 = 0, t2 = 0, t3 = 0;
  u64 m = bm[(size_t)i * 64 + lane];
  const int qbase = ((lane >> 2) << 8) | (lane & 3);
  while (m) {
    const int bp = __builtin_ctzll(m);
    m &= m - 1;
    const float xj = xh[qbase + (bp << 2)];
    float e0 = A0 + c20 * xj, e1 = A1 + c21 * xj, e2 = A2 + c22 * xj, e3 = A3 + c23 * xj;
    e0 = fmaxf(e0, 0.2f * e0); e1 = fmaxf(e1, 0.2f * e1);
    e2 = fmaxf(e2, 0.2f * e2); e3 = fmaxf(e3, 0.2f * e3);
    const float w0 = expf(e0), w1 = expf(e1), w2 = expf(e2), w3 = expf(e3);
    s0 += w0; s1 += w1; s2 += w2; s3 += w3;
    t0 += w0 * xj; t1 += w1 * xj; t2 += w2 * xj; t3 += w3 * xj;
  }
  for (int o = 1; o < 64; o <<= 1) {
    s0 += __shfl_xor(s0, o); s1 += __shfl_xor(s1, o);
    s2 += __shfl_xor(s2, o); s3 += __shfl_xor(s3, o);
    t0 += __shfl_xor(t0, o); t1 += __shfl_xor(t1, o);
    t2 += __shfl_xor(t2, o); t3 += __shfl_xor(t3, o);
  }
  float r0, r1, r2, r3;
  if (s0 != 0.f) { r0 = t0 / s0; r1 = t1 / s1; r2 = t2 / s2; r3 = t3 / s3; }
  else {
    float a = 0.f;
    for (int k = lane; k < 4096; k += 64) a += xh[k];
    for (int o = 1; o < 64; o <<= 1) a += __shfl_xor(a, o);
    r0 = r1 = r2 = r3 = a * (1.f / 4096.f);
  }
  if (lane == 0)
    wh2[i] = consts[8] * r0 + consts[9] * r1 + consts[10] * r2 + consts[11] * r3;
}

__global__ __launch_bounds__(256) void gat_out_bm(const u64* __restrict__ bm,
    const float* __restrict__ wh2, const float* __restrict__ consts,
    float* __restrict__ yhat) {
  const int lane = threadIdx.x & 63;
  const int i = blockIdx.x * 4 + (threadIdx.x >> 6);
  const float Ai = consts[12] * wh2[i];
  const float oa1 = consts[13];
  float s = 0.f, t = 0.f;
  u64 m = bm[(size_t)i * 64 + lane];
  const int qbase = ((lane >> 2) << 8) | (lane & 3);
  while (m) {
    const int bp = __builtin_ctzll(m);
    m &= m - 1;
    const float wj = wh2[qbase + (bp << 2)];
    float e = Ai + oa1 * wj;
    e = fmaxf(e, 0.2f * e);
    const float ww = expf(e);
    s += ww; t += ww * wj;
  }
  for (int o = 1; o < 64; o <<= 1) {
    s += __shfl_xor(s, o);
    t += __shfl_xor(t, o);
  }
  float v;
  if (s != 0.f) v = t / s;
  else {
    float a = 0.f;
    for (int k = lane; k < 4096; k += 64) a += wh2[k];
    for (int o = 1; o < 64; o <<= 1) a += __shfl_xor(a, o);
    v = a * (1.f / 4096.f);
  }
  if (lane == 0) yhat[i] = v > 0.f ? v : expm1f(v);
}
// =============================================================================

extern "C" void kernel_launch(void* const* d_in, const int* in_sizes, int n_in,
                              void* d_out, int out_size, void* d_ws, size_t ws_size,
                              hipStream_t stream) {
  const float* x      = (const float*)d_in[0];
  const float* eps    = (const float*)d_in[1];
  const void*  adj    = d_in[2];
  const float* enc_w1 = (const float*)d_in[3];
  const float* enc_b1 = (const float*)d_in[4];
  const float* enc_w2 = (const float*)d_in[5];
  const float* enc_b2 = (const float*)d_in[6];
  const float* enc_w3 = (const float*)d_in[7];
  const float* enc_b3 = (const float*)d_in[8];
  const float* enc_w4 = (const float*)d_in[9];
  const float* enc_b4 = (const float*)d_in[10];
  const float* dec_w1 = (const float*)d_in[11];
  const float* dec_b1 = (const float*)d_in[12];
  const float* dec_w2 = (const float*)d_in[13];
  const float* dec_b2 = (const float*)d_in[14];
  const float* dec_w3 = (const float*)d_in[15];
  const float* dec_b3 = (const float*)d_in[16];
  const float* gat_W  = (const float*)d_in[17];
  const float* gat_a  = (const float*)d_in[18];
  const float* out_W  = (const float*)d_in[19];
  const float* out_a  = (const float*)d_in[20];

  float* out    = (float*)d_out;
  float* xhat   = out;          // [0,4096)
  float* yhat   = out + 4096;   // [4096,8192)
  float* mu     = out + 8192;   // [8192,8704)
  float* logvar = out + 8704;   // [8704,9216)

  const size_t BM_BYTES = (size_t)4096 * 64 * sizeof(u64);  // 2 MiB
  u64*      bm     = (u64*)d_ws;
  float*    F      = (float*)((char*)d_ws + BM_BYTES);
  float*    h1     = F;            // 1024
  float*    h2     = F + 1024;     // 1024
  float*    h3     = F + 2048;     // 1024
  float*    h4     = F + 3072;     // 1024
  float*    wh2    = F + 4096;     // 4096
  float*    consts = F + 8208;     // 14
  int*      flag   = (int*)(F + 8224);
  unsigned* bars   = (unsigned*)(F + 8240);  // 8 slots x 16 uints

  prep_sniff_kernel<<<1, 256, 0, stream>>>(gat_W, gat_a, out_W, out_a,
                                           (const uint32_t*)adj, consts, flag, bars);

  P prm;
  prm.x = x; prm.eps = eps; prm.adj = adj;
  prm.w1 = enc_w1; prm.b1 = enc_b1; prm.w2 = enc_w2; prm.b2 = enc_b2;
  prm.w3 = enc_w3; prm.b3 = enc_b3; prm.w4 = enc_w4; prm.b4 = enc_b4;
  prm.dw1 = dec_w1; prm.db1 = dec_b1; prm.dw2 = dec_w2; prm.db2 = dec_b2;
  prm.dw3 = dec_w3; prm.db3 = dec_b3;
  prm.xhat = xhat; prm.yhat = yhat; prm.mu = mu; prm.logvar = logvar;
  prm.bm = bm; prm.h1 = h1; prm.h2 = h2; prm.h3 = h3; prm.h4 = h4;
  prm.wh2 = wh2; prm.consts = consts; prm.flag = flag; prm.bars = bars;
  void* kargs[] = { (void*)&prm };

  const hipError_t ce = hipLaunchCooperativeKernel(
      (const void*)fused_kernel, dim3(512), dim3(256), kargs, 0, stream);

  if (ce != hipSuccess) {
    // -------- fallback: proven round-2 multi-kernel pipeline --------
    conv_kernel<<<1024, 256, 0, stream>>>(adj, flag, bm);
    mv_kernel<ACT_RELU><<<1024, 256, 0, stream>>>(enc_w1, x,  enc_b1, h1, 4096);
    mv_kernel<ACT_RELU><<<1024, 256, 0, stream>>>(enc_w2, h1, enc_b2, h2, 1024);
    mulv_kernel<<<1024, 256, 0, stream>>>(enc_w3, enc_b3, enc_w4, enc_b4, h2, mu, logvar);
    dec1_kernel<<<1024, 256, 0, stream>>>(dec_w1, mu, logvar, eps, dec_b1, h3);
    mv_kernel<ACT_RELU><<<1024, 256, 0, stream>>>(dec_w2, h3, dec_b2, h4, 1024);
    mv_kernel<ACT_SIG ><<<4096, 256, 0, stream>>>(dec_w3, h4, dec_b3, xhat, 1024);
    gat_heads_bm<<<1024, 256, 0, stream>>>(bm, xhat, consts, wh2);
    gat_out_bm<<<1024, 256, 0, stream>>>(bm, wh2, consts, yhat);
  }
}

// Round 5
// 64.182 us; speedup vs baseline: 7.8039x; 7.5400x over previous
//
#include <hip/hip_runtime.h>
#include <cstdint>
#include <cstddef>

// ---------------------------------------------------------------------------
// DeepIM: VAE (matvec chain) + 2-layer GAT on 1%-dense adjacency.
//  - GAT heads are rank-1 => logits e[i,j]=leaky(c1*xh[i]+c2*xh[j]); head
//    outputs collapse to scalars. No NxN / Nx64 intermediates.
//  - adjacency -> 2MB bitmap (permuted bit mapping), scanned with ctz.
//  - R5: multi-kernel pipeline (R3/R4 lesson: 512-block spin barriers cost
//    ~70us each on MI355X; dispatch boundaries are ~2us — use the stream).
//    conv is piggybacked as extra independent blocks on the first 4 VAE
//    kernels (stream order guarantees bitmap ready before gat_heads).
// ---------------------------------------------------------------------------

typedef unsigned long long u64;

#define ACT_NONE 0
#define ACT_RELU 1
#define ACT_SIG  2

__device__ __forceinline__ float d4(float4 a, float4 b) {
  return a.x * b.x + a.y * b.y + a.z * b.z + a.w * b.w;
}
__device__ __forceinline__ float waveRed(float v) {
  for (int o = 32; o; o >>= 1) v += __shfl_down(v, o);
  return v;  // lane 0 holds sum
}

// conv: one adjacency row -> 64 bitmap words, permuted mapping:
//   bm word q (=it*4+c), bit b  <->  column (q>>2)*256 + 4*b + (q&3)
__device__ __forceinline__ void convRowInt(const uint4* aw, u64* bm, int r, int lane) {
  const uint4* rp = aw + (size_t)r * 1024u;
#pragma unroll
  for (int it = 0; it < 16; ++it) {
    const uint4 v = rp[it * 64 + lane];
    const u64 m0 = __ballot(v.x != 0u);
    const u64 m1 = __ballot(v.y != 0u);
    const u64 m2 = __ballot(v.z != 0u);
    const u64 m3 = __ballot(v.w != 0u);
    if (lane < 4) {
      const u64 mv = lane == 0 ? m0 : lane == 1 ? m1 : lane == 2 ? m2 : m3;
      bm[(size_t)r * 64 + it * 4 + lane] = mv;
    }
  }
}
__device__ __forceinline__ void convRowByte(const uint32_t* ab, u64* bm, int r, int lane) {
  const uint32_t* rp = ab + (size_t)r * 1024u;  // 4096 bytes
#pragma unroll
  for (int it = 0; it < 16; ++it) {
    const uint32_t v = rp[it * 64 + lane];
    const u64 m0 = __ballot((v & 0x000000ffu) != 0u);
    const u64 m1 = __ballot((v & 0x0000ff00u) != 0u);
    const u64 m2 = __ballot((v & 0x00ff0000u) != 0u);
    const u64 m3 = __ballot((v & 0xff000000u) != 0u);
    if (lane < 4) {
      const u64 mv = lane == 0 ? m0 : lane == 1 ? m1 : lane == 2 ? m2 : m3;
      bm[(size_t)r * 64 + it * 4 + lane] = mv;
    }
  }
}
__device__ __forceinline__ void convRow(const void* adj, int fl, u64* bm, int r, int lane) {
  if (fl) convRowByte((const uint32_t*)adj, bm, r, lane);
  else    convRowInt((const uint4*)adj, bm, r, lane);
}

// Handle blockIdx >= R as a conv block (4 rows, 1/wave). Returns true if conv.
__device__ __forceinline__ bool convSide(int R, int convBase, const void* adj,
                                         const int* flag, u64* bm) {
  if ((int)blockIdx.x < R) return false;
  const int blk = blockIdx.x - R;
  const int row = convBase + blk * 4 + (threadIdx.x >> 6);
  convRow(adj, *flag, bm, row, threadIdx.x & 63);
  return true;
}

// y[r] = act(dot(W[r,:], x) + b[r]); blocks [0,R) = matvec rows, [R,R+CB) = conv.
template<int ACT>
__global__ __launch_bounds__(256) void mv_conv_kernel(const float* __restrict__ W,
    const float* __restrict__ x, const float* __restrict__ b,
    float* __restrict__ y, int C, int R, int convBase,
    const void* __restrict__ adj, const int* __restrict__ flag,
    u64* __restrict__ bm) {
  if (convSide(R, convBase, adj, flag, bm)) return;
  const int r = blockIdx.x;
  const float* row = W + (size_t)r * (size_t)C;
  float acc = 0.f;
  for (int c = threadIdx.x * 4; c < C; c += 256 * 4) {
    const float4 w4 = *reinterpret_cast<const float4*>(row + c);
    const float4 x4 = *reinterpret_cast<const float4*>(x + c);
    acc += d4(w4, x4);
  }
  acc = waveRed(acc);
  __shared__ float lds[4];
  if ((threadIdx.x & 63) == 0) lds[threadIdx.x >> 6] = acc;
  __syncthreads();
  if (threadIdx.x == 0) {
    float v = lds[0] + lds[1] + lds[2] + lds[3] + b[r];
    if (ACT == ACT_RELU) v = v > 0.f ? v : 0.f;
    if (ACT == ACT_SIG)  v = 1.f / (1.f + expf(-v));
    y[r] = v;
  }
}

// mu (rows 0..511 via w3) and logvar (rows 512..1023 via w4) + conv side-work.
__global__ __launch_bounds__(256) void mulv_conv_kernel(const float* __restrict__ w3,
    const float* __restrict__ b3, const float* __restrict__ w4,
    const float* __restrict__ b4, const float* __restrict__ h2,
    float* __restrict__ mu, float* __restrict__ logvar, int convBase,
    const void* __restrict__ adj, const int* __restrict__ flag,
    u64* __restrict__ bm) {
  if (convSide(1024, convBase, adj, flag, bm)) return;
  const int r = blockIdx.x;
  const bool is_mu = r < 512;
  const int rr = is_mu ? r : r - 512;
  const float* row = (is_mu ? w3 : w4) + (size_t)rr * 1024u;
  const int c = threadIdx.x * 4;
  float acc = d4(*reinterpret_cast<const float4*>(row + c),
                 *reinterpret_cast<const float4*>(h2 + c));
  acc = waveRed(acc);
  __shared__ float lds[4];
  if ((threadIdx.x & 63) == 0) lds[threadIdx.x >> 6] = acc;
  __syncthreads();
  if (threadIdx.x == 0) {
    const float v = lds[0] + lds[1] + lds[2] + lds[3] + (is_mu ? b3[rr] : b4[rr]);
    (is_mu ? mu : logvar)[rr] = v;
  }
}

// dec1 with z = mu + eps*exp(0.5*logvar) computed in LDS + conv side-work.
__global__ __launch_bounds__(256) void dec1_conv_kernel(const float* __restrict__ W,
    const float* __restrict__ mu, const float* __restrict__ logvar,
    const float* __restrict__ eps, const float* __restrict__ b,
    float* __restrict__ y, int convBase, const void* __restrict__ adj,
    const int* __restrict__ flag, u64* __restrict__ bm) {
  if (convSide(1024, convBase, adj, flag, bm)) return;
  __shared__ float zsh[512];
  for (int k = threadIdx.x; k < 512; k += 256)
    zsh[k] = mu[k] + eps[k] * expf(0.5f * logvar[k]);
  __syncthreads();
  const int r = blockIdx.x;
  const float* row = W + (size_t)r * 512u;
  const int c = threadIdx.x * 2;
  const float2 w2 = *reinterpret_cast<const float2*>(row + c);
  float acc = w2.x * zsh[c] + w2.y * zsh[c + 1];
  acc = waveRed(acc);
  __shared__ float lds[4];
  if ((threadIdx.x & 63) == 0) lds[threadIdx.x >> 6] = acc;
  __syncthreads();
  if (threadIdx.x == 0) {
    float v = lds[0] + lds[1] + lds[2] + lds[3] + b[r];
    y[r] = v > 0.f ? v : 0.f;
  }
}

// Per-head scalars + adjacency format sniff.
// consts layout: [c1(4), c2(4), d(4), oa0, oa1]
__global__ __launch_bounds__(256) void prep_sniff_kernel(const float* __restrict__ gw,
    const float* __restrict__ ga, const float* __restrict__ ow,
    const float* __restrict__ oa, const uint32_t* __restrict__ aw,
    float* __restrict__ consts, int* __restrict__ flag) {
  const int t = threadIdx.x, h = t >> 6, k = t & 63;
  const float w = gw[h * 64 + k];
  float p1 = w * ga[h * 128 + k];
  float p2 = w * ga[h * 128 + 64 + k];
  float p3 = w * ow[h * 64 + k];
  for (int off = 32; off; off >>= 1) {
    p1 += __shfl_down(p1, off);
    p2 += __shfl_down(p2, off);
    p3 += __shfl_down(p3, off);
  }
  if (k == 0) { consts[h] = p1; consts[4 + h] = p2; consts[8 + h] = p3; }
  if (t == 0) { consts[12] = oa[0]; consts[13] = oa[1]; }
  // sniff first 64KB (in-bounds under either layout):
  // any word not in {0,1,1.0f} proves packed-byte layout.
  int bad = 0;
  for (int i = t; i < 16384; i += 256) {
    const uint32_t v = aw[i];
    bad |= (v > 1u) && (v != 0x3F800000u);
  }
  __shared__ int lds[4];
  const unsigned long long mm = __ballot(bad);
  if ((t & 63) == 0) lds[t >> 6] = (mm != 0ull) ? 1 : 0;
  __syncthreads();
  if (t == 0) flag[0] = lds[0] | lds[1] | lds[2] | lds[3];
}

// 4 heads fused, bitmap scan. One wave per row; lane = bitmap word index.
__global__ __launch_bounds__(256) void gat_heads_bm(const u64* __restrict__ bm,
    const float* __restrict__ xh, const float* __restrict__ consts,
    float* __restrict__ wh2) {
  const int lane = threadIdx.x & 63;
  const int i = blockIdx.x * 4 + (threadIdx.x >> 6);
  const float xi = xh[i];
  const float A0 = consts[0] * xi, A1 = consts[1] * xi,
              A2 = consts[2] * xi, A3 = consts[3] * xi;
  const float c20 = consts[4], c21 = consts[5], c22 = consts[6], c23 = consts[7];
  float s0 = 0, s1 = 0, s2 = 0, s3 = 0, t0 = 0, t1 = 0, t2 = 0, t3 = 0;
  u64 m = bm[(size_t)i * 64 + lane];
  const int qbase = ((lane >> 2) << 8) | (lane & 3);
  while (m) {
    const int bp = __builtin_ctzll(m);
    m &= m - 1;
    const float xj = xh[qbase + (bp << 2)];
    float e0 = A0 + c20 * xj, e1 = A1 + c21 * xj, e2 = A2 + c22 * xj, e3 = A3 + c23 * xj;
    e0 = fmaxf(e0, 0.2f * e0); e1 = fmaxf(e1, 0.2f * e1);
    e2 = fmaxf(e2, 0.2f * e2); e3 = fmaxf(e3, 0.2f * e3);
    const float w0 = expf(e0), w1 = expf(e1), w2 = expf(e2), w3 = expf(e3);
    s0 += w0; s1 += w1; s2 += w2; s3 += w3;
    t0 += w0 * xj; t1 += w1 * xj; t2 += w2 * xj; t3 += w3 * xj;
  }
  for (int o = 1; o < 64; o <<= 1) {
    s0 += __shfl_xor(s0, o); s1 += __shfl_xor(s1, o);
    s2 += __shfl_xor(s2, o); s3 += __shfl_xor(s3, o);
    t0 += __shfl_xor(t0, o); t1 += __shfl_xor(t1, o);
    t2 += __shfl_xor(t2, o); t3 += __shfl_xor(t3, o);
  }
  float r0, r1, r2, r3;
  if (s0 != 0.f) { r0 = t0 / s0; r1 = t1 / s1; r2 = t2 / s2; r3 = t3 / s3; }
  else {  // empty row -> uniform attention (mean of xh)
    float a = 0.f;
    for (int k = lane; k < 4096; k += 64) a += xh[k];
    for (int o = 1; o < 64; o <<= 1) a += __shfl_xor(a, o);
    r0 = r1 = r2 = r3 = a * (1.f / 4096.f);
  }
  if (lane == 0)
    wh2[i] = consts[8] * r0 + consts[9] * r1 + consts[10] * r2 + consts[11] * r3;
}

// Output GAT layer (f=1), bitmap scan. y = elu(att @ Wh2).
__global__ __launch_bounds__(256) void gat_out_bm(const u64* __restrict__ bm,
    const float* __restrict__ wh2, const float* __restrict__ consts,
    float* __restrict__ yhat) {
  const int lane = threadIdx.x & 63;
  const int i = blockIdx.x * 4 + (threadIdx.x >> 6);
  const float Ai = consts[12] * wh2[i];
  const float oa1 = consts[13];
  float s = 0.f, t = 0.f;
  u64 m = bm[(size_t)i * 64 + lane];
  const int qbase = ((lane >> 2) << 8) | (lane & 3);
  while (m) {
    const int bp = __builtin_ctzll(m);
    m &= m - 1;
    const float wj = wh2[qbase + (bp << 2)];
    float e = Ai + oa1 * wj;
    e = fmaxf(e, 0.2f * e);
    const float ww = expf(e);
    s += ww; t += ww * wj;
  }
  for (int o = 1; o < 64; o <<= 1) {
    s += __shfl_xor(s, o);
    t += __shfl_xor(t, o);
  }
  float v;
  if (s != 0.f) v = t / s;
  else {
    float a = 0.f;
    for (int k = lane; k < 4096; k += 64) a += wh2[k];
    for (int o = 1; o < 64; o <<= 1) a += __shfl_xor(a, o);
    v = a * (1.f / 4096.f);
  }
  if (lane == 0) yhat[i] = v > 0.f ? v : expm1f(v);
}

extern "C" void kernel_launch(void* const* d_in, const int* in_sizes, int n_in,
                              void* d_out, int out_size, void* d_ws, size_t ws_size,
                              hipStream_t stream) {
  const float* x      = (const float*)d_in[0];
  const float* eps    = (const float*)d_in[1];
  const void*  adj    = d_in[2];
  const float* enc_w1 = (const float*)d_in[3];
  const float* enc_b1 = (const float*)d_in[4];
  const float* enc_w2 = (const float*)d_in[5];
  const float* enc_b2 = (const float*)d_in[6];
  const float* enc_w3 = (const float*)d_in[7];
  const float* enc_b3 = (const float*)d_in[8];
  const float* enc_w4 = (const float*)d_in[9];
  const float* enc_b4 = (const float*)d_in[10];
  const float* dec_w1 = (const float*)d_in[11];
  const float* dec_b1 = (const float*)d_in[12];
  const float* dec_w2 = (const float*)d_in[13];
  const float* dec_b2 = (const float*)d_in[14];
  const float* dec_w3 = (const float*)d_in[15];
  const float* dec_b3 = (const float*)d_in[16];
  const float* gat_W  = (const float*)d_in[17];
  const float* gat_a  = (const float*)d_in[18];
  const float* out_W  = (const float*)d_in[19];
  const float* out_a  = (const float*)d_in[20];

  float* out    = (float*)d_out;
  float* xhat   = out;          // [0,4096)
  float* yhat   = out + 4096;   // [4096,8192)
  float* mu     = out + 8192;   // [8192,8704)
  float* logvar = out + 8704;   // [8704,9216)

  const size_t BM_BYTES = (size_t)4096 * 64 * sizeof(u64);  // 2 MiB
  u64*   bm     = (u64*)d_ws;
  float* F      = (float*)((char*)d_ws + BM_BYTES);
  float* h1     = F;            // 1024
  float* h2     = F + 1024;     // 1024
  float* h3     = F + 2048;     // 1024
  float* h4     = F + 3072;     // 1024
  float* wh2    = F + 4096;     // 4096
  float* consts = F + 8208;     // 14
  int*   flag   = (int*)(F + 8224);

  prep_sniff_kernel<<<1, 256, 0, stream>>>(gat_W, gat_a, out_W, out_a,
                                           (const uint32_t*)adj, consts, flag);

  // VAE chain; conv piggybacked as +256 independent blocks on first 4 stages
  // (1024 adjacency rows each; bitmap complete after dec1, used 2 stages later).
  mv_conv_kernel<ACT_RELU><<<1024 + 256, 256, 0, stream>>>(
      enc_w1, x, enc_b1, h1, 4096, 1024, 0, adj, flag, bm);
  mv_conv_kernel<ACT_RELU><<<1024 + 256, 256, 0, stream>>>(
      enc_w2, h1, enc_b2, h2, 1024, 1024, 1024, adj, flag, bm);
  mulv_conv_kernel<<<1024 + 256, 256, 0, stream>>>(
      enc_w3, enc_b3, enc_w4, enc_b4, h2, mu, logvar, 2048, adj, flag, bm);
  dec1_conv_kernel<<<1024 + 256, 256, 0, stream>>>(
      dec_w1, mu, logvar, eps, dec_b1, h3, 3072, adj, flag, bm);
  mv_conv_kernel<ACT_RELU><<<1024, 256, 0, stream>>>(
      dec_w2, h3, dec_b2, h4, 1024, 1024, 0, adj, flag, bm);  // no conv side
  mv_conv_kernel<ACT_SIG><<<4096, 256, 0, stream>>>(
      dec_w3, h4, dec_b3, xhat, 1024, 4096, 0, adj, flag, bm);  // no conv side

  // GAT (bitmap guaranteed complete by stream order)
  gat_heads_bm<<<1024, 256, 0, stream>>>(bm, xhat, consts, wh2);
  gat_out_bm<<<1024, 256, 0, stream>>>(bm, wh2, consts, yhat);
}

// Round 6
// 44.297 us; speedup vs baseline: 11.3071x; 1.4489x over previous
//
#include <hip/hip_runtime.h>
#include <cstdint>
#include <cstddef>

// ---------------------------------------------------------------------------
// DeepIM: VAE (matvec chain) + 2-layer GAT on 1%-dense adjacency.
//  - GAT heads are rank-1 => logits e[i,j]=leaky(c1*xh[i]+c2*xh[j]); head
//    outputs collapse to scalars. No NxN / Nx64 intermediates.
//  - adjacency (int32/float32 words, counter-confirmed R1: FETCH 33MB > 16.7MB
//    rules out packed bytes) -> 2MB bitmap (permuted mapping), ctz-scanned.
//  - R6 structure: 8 dispatches. Dispatch 1 = mega kernel: conv (1024 blocks,
//    the proven full-BW shape) + enc1 (1024 blocks) + prep (1 block) all
//    independent; stream order covers every later dependency.
//  - R3/R4 lesson: 512-block device-scope spin barriers cost ~70us each on
//    MI355X — never hand-roll grid sync here; use dispatch boundaries.
//  - R5 lesson: piggybacked work needs enough blocks to saturate its own
//    regime (conv at 256 blocks runs ~4x slower aggregate).
// ---------------------------------------------------------------------------

typedef unsigned long long u64;

#define ACT_NONE 0
#define ACT_RELU 1
#define ACT_SIG  2

__device__ __forceinline__ float d4(float4 a, float4 b) {
  return a.x * b.x + a.y * b.y + a.z * b.z + a.w * b.w;
}
__device__ __forceinline__ float waveRed(float v) {
  for (int o = 32; o; o >>= 1) v += __shfl_down(v, o);
  return v;  // lane 0 holds sum
}

// conv: one adjacency row (4096 int32 words) -> 64 bitmap words, permuted:
//   bm word q (=it*4+c), bit b  <->  column (q>>2)*256 + 4*b + (q&3)
__device__ __forceinline__ void convRow(const uint4* aw, u64* bm, int r, int lane) {
  const uint4* rp = aw + (size_t)r * 1024u;
#pragma unroll
  for (int it = 0; it < 16; ++it) {
    const uint4 v = rp[it * 64 + lane];
    const u64 m0 = __ballot(v.x != 0u);
    const u64 m1 = __ballot(v.y != 0u);
    const u64 m2 = __ballot(v.z != 0u);
    const u64 m3 = __ballot(v.w != 0u);
    if (lane < 4) {
      const u64 mv = lane == 0 ? m0 : lane == 1 ? m1 : lane == 2 ? m2 : m3;
      bm[(size_t)r * 64 + it * 4 + lane] = mv;
    }
  }
}

// Mega dispatch #1: blocks [0,1024) conv (4 rows each, 1 row/wave);
// [1024,2048) enc1 rows r-1024 (relu(enc_w1 @ x + b1));
// block 2048: GAT prep scalars. All mutually independent.
struct MegaP {
  const void* adj;
  u64* bm;
  const float *w1, *x, *b1;
  float* h1;
  const float *gw, *ga, *ow, *oa;
  float* consts;  // [c1(4), c2(4), d(4), oa0, oa1]
};

__global__ __launch_bounds__(256) void mega_kernel(MegaP p) {
  const int tid = threadIdx.x, w = tid >> 6, lane = tid & 63;
  const int blk = blockIdx.x;
  if (blk < 1024) {                        // ---- conv: rows blk*4 + w
    convRow((const uint4*)p.adj, p.bm, blk * 4 + w, lane);
    return;
  }
  if (blk < 2048) {                        // ---- enc1 row
    const int r = blk - 1024;
    const float4* row = (const float4*)(p.w1 + (size_t)r * 4096u);
    const float4* x4 = (const float4*)p.x;
    float acc = 0.f;
#pragma unroll
    for (int k = 0; k < 4; ++k) {
      const int idx = tid + 256 * k;
      acc += d4(row[idx], x4[idx]);
    }
    acc = waveRed(acc);
    __shared__ float lds[4];
    if (lane == 0) lds[w] = acc;
    __syncthreads();
    if (tid == 0) {
      const float v = lds[0] + lds[1] + lds[2] + lds[3] + p.b1[r];
      p.h1[r] = v > 0.f ? v : 0.f;
    }
    return;
  }
  // ---- prep: per-head scalars (1 block)
  const int h = w, k = lane;
  const float wv = p.gw[h * 64 + k];
  float p1 = wv * p.ga[h * 128 + k];
  float p2 = wv * p.ga[h * 128 + 64 + k];
  float p3 = wv * p.ow[h * 64 + k];
  for (int off = 32; off; off >>= 1) {
    p1 += __shfl_down(p1, off);
    p2 += __shfl_down(p2, off);
    p3 += __shfl_down(p3, off);
  }
  if (k == 0) { p.consts[h] = p1; p.consts[4 + h] = p2; p.consts[8 + h] = p3; }
  if (tid == 0) { p.consts[12] = p.oa[0]; p.consts[13] = p.oa[1]; }
}

// y[r] = act( dot(W[r,:], x) + b[r] );  one block (256 thr) per row.
template<int ACT>
__global__ __launch_bounds__(256) void mv_kernel(const float* __restrict__ W,
    const float* __restrict__ x, const float* __restrict__ b,
    float* __restrict__ y, int C) {
  const int r = blockIdx.x;
  const float* row = W + (size_t)r * (size_t)C;
  float acc = 0.f;
  for (int c = threadIdx.x * 4; c < C; c += 256 * 4) {
    const float4 w4 = *reinterpret_cast<const float4*>(row + c);
    const float4 x4 = *reinterpret_cast<const float4*>(x + c);
    acc += d4(w4, x4);
  }
  acc = waveRed(acc);
  __shared__ float lds[4];
  if ((threadIdx.x & 63) == 0) lds[threadIdx.x >> 6] = acc;
  __syncthreads();
  if (threadIdx.x == 0) {
    float v = lds[0] + lds[1] + lds[2] + lds[3] + b[r];
    if (ACT == ACT_RELU) v = v > 0.f ? v : 0.f;
    if (ACT == ACT_SIG)  v = 1.f / (1.f + expf(-v));
    y[r] = v;
  }
}

// mu (rows 0..511 via w3) and logvar (rows 512..1023 via w4) in one grid.
__global__ __launch_bounds__(256) void mulv_kernel(const float* __restrict__ w3,
    const float* __restrict__ b3, const float* __restrict__ w4,
    const float* __restrict__ b4, const float* __restrict__ h2,
    float* __restrict__ mu, float* __restrict__ logvar) {
  const int r = blockIdx.x;
  const bool is_mu = r < 512;
  const int rr = is_mu ? r : r - 512;
  const float* row = (is_mu ? w3 : w4) + (size_t)rr * 1024u;
  const int c = threadIdx.x * 4;
  float acc = d4(*reinterpret_cast<const float4*>(row + c),
                 *reinterpret_cast<const float4*>(h2 + c));
  acc = waveRed(acc);
  __shared__ float lds[4];
  if ((threadIdx.x & 63) == 0) lds[threadIdx.x >> 6] = acc;
  __syncthreads();
  if (threadIdx.x == 0) {
    const float v = lds[0] + lds[1] + lds[2] + lds[3] + (is_mu ? b3[rr] : b4[rr]);
    (is_mu ? mu : logvar)[rr] = v;
  }
}

// dec1 with z = mu + eps*exp(0.5*logvar) computed in LDS per block.
__global__ __launch_bounds__(256) void dec1_kernel(const float* __restrict__ W,
    const float* __restrict__ mu, const float* __restrict__ logvar,
    const float* __restrict__ eps, const float* __restrict__ b,
    float* __restrict__ y) {
  __shared__ float zsh[512];
  for (int k = threadIdx.x; k < 512; k += 256)
    zsh[k] = mu[k] + eps[k] * expf(0.5f * logvar[k]);
  __syncthreads();
  const int r = blockIdx.x;
  const float* row = W + (size_t)r * 512u;
  const int c = threadIdx.x * 2;
  const float2 w2 = *reinterpret_cast<const float2*>(row + c);
  float acc = w2.x * zsh[c] + w2.y * zsh[c + 1];
  acc = waveRed(acc);
  __shared__ float lds[4];
  if ((threadIdx.x & 63) == 0) lds[threadIdx.x >> 6] = acc;
  __syncthreads();
  if (threadIdx.x == 0) {
    float v = lds[0] + lds[1] + lds[2] + lds[3] + b[r];
    y[r] = v > 0.f ? v : 0.f;
  }
}

// 4 heads fused, bitmap scan. One wave per row; lane = bitmap word index.
__global__ __launch_bounds__(256) void gat_heads_bm(const u64* __restrict__ bm,
    const float* __restrict__ xh, const float* __restrict__ consts,
    float* __restrict__ wh2) {
  const int lane = threadIdx.x & 63;
  const int i = blockIdx.x * 4 + (threadIdx.x >> 6);
  const float xi = xh[i];
  const float A0 = consts[0] * xi, A1 = consts[1] * xi,
              A2 = consts[2] * xi, A3 = consts[3] * xi;
  const float c20 = consts[4], c21 = consts[5], c22 = consts[6], c23 = consts[7];
  float s0 = 0, s1 = 0, s2 = 0, s3 = 0, t0 = 0, t1 = 0, t2 = 0, t3 = 0;
  u64 m = bm[(size_t)i * 64 + lane];
  const int qbase = ((lane >> 2) << 8) | (lane & 3);
  while (m) {
    const int bp = __builtin_ctzll(m);
    m &= m - 1;
    const float xj = xh[qbase + (bp << 2)];
    float e0 = A0 + c20 * xj, e1 = A1 + c21 * xj, e2 = A2 + c22 * xj, e3 = A3 + c23 * xj;
    e0 = fmaxf(e0, 0.2f * e0); e1 = fmaxf(e1, 0.2f * e1);
    e2 = fmaxf(e2, 0.2f * e2); e3 = fmaxf(e3, 0.2f * e3);
    const float w0 = expf(e0), w1 = expf(e1), w2 = expf(e2), w3 = expf(e3);
    s0 += w0; s1 += w1; s2 += w2; s3 += w3;
    t0 += w0 * xj; t1 += w1 * xj; t2 += w2 * xj; t3 += w3 * xj;
  }
  for (int o = 1; o < 64; o <<= 1) {
    s0 += __shfl_xor(s0, o); s1 += __shfl_xor(s1, o);
    s2 += __shfl_xor(s2, o); s3 += __shfl_xor(s3, o);
    t0 += __shfl_xor(t0, o); t1 += __shfl_xor(t1, o);
    t2 += __shfl_xor(t2, o); t3 += __shfl_xor(t3, o);
  }
  float r0, r1, r2, r3;
  if (s0 != 0.f) { r0 = t0 / s0; r1 = t1 / s1; r2 = t2 / s2; r3 = t3 / s3; }
  else {  // empty row -> uniform attention (mean of xh)
    float a = 0.f;
    for (int k = lane; k < 4096; k += 64) a += xh[k];
    for (int o = 1; o < 64; o <<= 1) a += __shfl_xor(a, o);
    r0 = r1 = r2 = r3 = a * (1.f / 4096.f);
  }
  if (lane == 0)
    wh2[i] = consts[8] * r0 + consts[9] * r1 + consts[10] * r2 + consts[11] * r3;
}

// Output GAT layer (f=1), bitmap scan. y = elu(att @ Wh2).
__global__ __launch_bounds__(256) void gat_out_bm(const u64* __restrict__ bm,
    const float* __restrict__ wh2, const float* __restrict__ consts,
    float* __restrict__ yhat) {
  const int lane = threadIdx.x & 63;
  const int i = blockIdx.x * 4 + (threadIdx.x >> 6);
  const float Ai = consts[12] * wh2[i];
  const float oa1 = consts[13];
  float s = 0.f, t = 0.f;
  u64 m = bm[(size_t)i * 64 + lane];
  const int qbase = ((lane >> 2) << 8) | (lane & 3);
  while (m) {
    const int bp = __builtin_ctzll(m);
    m &= m - 1;
    const float wj = wh2[qbase + (bp << 2)];
    float e = Ai + oa1 * wj;
    e = fmaxf(e, 0.2f * e);
    const float ww = expf(e);
    s += ww; t += ww * wj;
  }
  for (int o = 1; o < 64; o <<= 1) {
    s += __shfl_xor(s, o);
    t += __shfl_xor(t, o);
  }
  float v;
  if (s != 0.f) v = t / s;
  else {
    float a = 0.f;
    for (int k = lane; k < 4096; k += 64) a += wh2[k];
    for (int o = 1; o < 64; o <<= 1) a += __shfl_xor(a, o);
    v = a * (1.f / 4096.f);
  }
  if (lane == 0) yhat[i] = v > 0.f ? v : expm1f(v);
}

extern "C" void kernel_launch(void* const* d_in, const int* in_sizes, int n_in,
                              void* d_out, int out_size, void* d_ws, size_t ws_size,
                              hipStream_t stream) {
  const float* x      = (const float*)d_in[0];
  const float* eps    = (const float*)d_in[1];
  const void*  adj    = d_in[2];
  const float* enc_w1 = (const float*)d_in[3];
  const float* enc_b1 = (const float*)d_in[4];
  const float* enc_w2 = (const float*)d_in[5];
  const float* enc_b2 = (const float*)d_in[6];
  const float* enc_w3 = (const float*)d_in[7];
  const float* enc_b3 = (const float*)d_in[8];
  const float* enc_w4 = (const float*)d_in[9];
  const float* enc_b4 = (const float*)d_in[10];
  const float* dec_w1 = (const float*)d_in[11];
  const float* dec_b1 = (const float*)d_in[12];
  const float* dec_w2 = (const float*)d_in[13];
  const float* dec_b2 = (const float*)d_in[14];
  const float* dec_w3 = (const float*)d_in[15];
  const float* dec_b3 = (const float*)d_in[16];
  const float* gat_W  = (const float*)d_in[17];
  const float* gat_a  = (const float*)d_in[18];
  const float* out_W  = (const float*)d_in[19];
  const float* out_a  = (const float*)d_in[20];

  float* out    = (float*)d_out;
  float* xhat   = out;          // [0,4096)
  float* yhat   = out + 4096;   // [4096,8192)
  float* mu     = out + 8192;   // [8192,8704)
  float* logvar = out + 8704;   // [8704,9216)

  const size_t BM_BYTES = (size_t)4096 * 64 * sizeof(u64);  // 2 MiB
  u64*   bm     = (u64*)d_ws;
  float* F      = (float*)((char*)d_ws + BM_BYTES);
  float* h1     = F;            // 1024
  float* h2     = F + 1024;     // 1024
  float* h3     = F + 2048;     // 1024
  float* h4     = F + 3072;     // 1024
  float* wh2    = F + 4096;     // 4096
  float* consts = F + 8208;     // 14

  // Dispatch 1: conv (1024 blocks) + enc1 (1024 blocks) + prep (1 block).
  MegaP mp;
  mp.adj = adj; mp.bm = bm;
  mp.w1 = enc_w1; mp.x = x; mp.b1 = enc_b1; mp.h1 = h1;
  mp.gw = gat_W; mp.ga = gat_a; mp.ow = out_W; mp.oa = out_a;
  mp.consts = consts;
  mega_kernel<<<2049, 256, 0, stream>>>(mp);

  // VAE chain (each stage depends fully on the previous).
  mv_kernel<ACT_RELU><<<1024, 256, 0, stream>>>(enc_w2, h1, enc_b2, h2, 1024);
  mulv_kernel<<<1024, 256, 0, stream>>>(enc_w3, enc_b3, enc_w4, enc_b4, h2, mu, logvar);
  dec1_kernel<<<1024, 256, 0, stream>>>(dec_w1, mu, logvar, eps, dec_b1, h3);
  mv_kernel<ACT_RELU><<<1024, 256, 0, stream>>>(dec_w2, h3, dec_b2, h4, 1024);
  mv_kernel<ACT_SIG ><<<4096, 256, 0, stream>>>(dec_w3, h4, dec_b3, xhat, 1024);

  // GAT (bitmap + consts ready since dispatch 1).
  gat_heads_bm<<<1024, 256, 0, stream>>>(bm, xhat, consts, wh2);
  gat_out_bm<<<1024, 256, 0, stream>>>(bm, wh2, consts, yhat);
}